// Round 7
// baseline (1888.295 us; speedup 1.0000x reference)
//
#include <hip/hip_runtime.h>

#define B_ 64
#define T_ 512
#define D_ 512
#define H_ 512
#define NG 2048  // 4H

typedef __attribute__((ext_vector_type(8))) short short8;
typedef __attribute__((ext_vector_type(4))) float floatx4;
typedef __attribute__((ext_vector_type(4))) unsigned int uintx4;

static __device__ __forceinline__ unsigned short f2bf(float f) {
    unsigned int u = __float_as_uint(f);
    return (unsigned short)((u + 0x7FFFu + ((u >> 16) & 1u)) >> 16);  // RNE
}

static __device__ __forceinline__ short8 pack8(float4 a, float4 b) {
    short8 r;
    r[0] = (short)f2bf(a.x); r[1] = (short)f2bf(a.y);
    r[2] = (short)f2bf(a.z); r[3] = (short)f2bf(a.w);
    r[4] = (short)f2bf(b.x); r[5] = (short)f2bf(b.y);
    r[6] = (short)f2bf(b.z); r[7] = (short)f2bf(b.w);
    return r;
}

static __device__ __forceinline__ float sigm(float x) { return 1.0f / (1.0f + __expf(-x)); }
static __device__ __forceinline__ float tanh_(float x) {
    float e = __expf(2.0f * x);
    return 1.0f - 2.0f / (e + 1.0f);
}

// ---- transpose Wi/Wh ([512][2048] f32) -> bf16 [2048][512], LDS-tiled ----
__global__ __launch_bounds__(256) void transpose_w(
    const float* __restrict__ Wi, const float* __restrict__ Wh,
    unsigned short* __restrict__ WiT, unsigned short* __restrict__ WhT)
{
    __shared__ float tile[64][65];
    const float* src = blockIdx.z ? Wh : Wi;
    unsigned short* dst = blockIdx.z ? WhT : WiT;
    const int n0 = blockIdx.x * 64, k0 = blockIdx.y * 64;
    const int cx = threadIdx.x & 63, ry = threadIdx.x >> 6;
#pragma unroll
    for (int i = 0; i < 16; ++i) {
        int k = ry * 16 + i;
        tile[k][cx] = src[(size_t)(k0 + k) * NG + n0 + cx];
    }
    __syncthreads();
#pragma unroll
    for (int i = 0; i < 16; ++i) {
        int n = ry * 16 + i;
        dst[(size_t)(n0 + n) * D_ + k0 + cx] = f2bf(tile[cx][n]);
    }
}

// ---- zx[b][t][4H] (fp16) = flip(x) @ Wi + b ; 128x128 tile, 4 waves ----
__global__ __launch_bounds__(256) void zx_gemm(
    const float* __restrict__ x, const int* __restrict__ lengths,
    const unsigned short* __restrict__ WiT, const float* __restrict__ bias,
    const int* __restrict__ revp, _Float16* __restrict__ zx)
{
    __shared__ unsigned short a_lds[128][40];
    __shared__ unsigned short b_lds[128][40];

    const int mt = blockIdx.x, nt = blockIdx.y;
    const int tid = threadIdx.x;
    const int lane = tid & 63, w = tid >> 6;
    const int wm = w & 1, wn = w >> 1;

    const int b = mt >> 2;
    const int len = lengths[b];
    const int rev = revp[0];

    const int r = tid >> 1;
    const int kh = (tid & 1) << 4;
    const int t = ((mt & 3) << 7) + r;
    const int src_t = rev ? ((T_ - 1 - t + len) & (T_ - 1)) : t;
    const float* arow = x + ((size_t)b * T_ + src_t) * D_;
    const unsigned short* brow = WiT + (size_t)(nt * 128 + r) * D_;

    floatx4 acc[4][4];
#pragma unroll
    for (int i = 0; i < 4; ++i)
#pragma unroll
        for (int j = 0; j < 4; ++j) acc[i][j] = (floatx4){0.f, 0.f, 0.f, 0.f};

    for (int kt = 0; kt < D_ / 32; ++kt) {
        const float4* ap = (const float4*)(arow + kt * 32 + kh);
        float4 a0 = ap[0], a1 = ap[1], a2 = ap[2], a3 = ap[3];
        const uint4* bp = (const uint4*)(brow + kt * 32 + kh);
        uint4 bq0 = bp[0], bq1 = bp[1];
        *(short8*)&a_lds[r][kh]     = pack8(a0, a1);
        *(short8*)&a_lds[r][kh + 8] = pack8(a2, a3);
        *(uint4*)&b_lds[r][kh]     = bq0;
        *(uint4*)&b_lds[r][kh + 8] = bq1;
        __syncthreads();

        short8 af[4], bfr[4];
#pragma unroll
        for (int mi = 0; mi < 4; ++mi)
            af[mi] = *(const short8*)&a_lds[wm * 64 + mi * 16 + (lane & 15)][(lane >> 4) << 3];
#pragma unroll
        for (int ni = 0; ni < 4; ++ni)
            bfr[ni] = *(const short8*)&b_lds[wn * 64 + ni * 16 + (lane & 15)][(lane >> 4) << 3];
#pragma unroll
        for (int mi = 0; mi < 4; ++mi)
#pragma unroll
            for (int ni = 0; ni < 4; ++ni)
                acc[mi][ni] = __builtin_amdgcn_mfma_f32_16x16x32_bf16(af[mi], bfr[ni], acc[mi][ni], 0, 0, 0);
        __syncthreads();
    }

#pragma unroll
    for (int mi = 0; mi < 4; ++mi) {
#pragma unroll
        for (int ni = 0; ni < 4; ++ni) {
            int row = wm * 64 + mi * 16 + ((lane >> 4) << 2);
            int col = nt * 128 + wn * 64 + ni * 16 + (lane & 15);
            float bv = bias[col];
            size_t base = (size_t)(mt * 128 + row) * NG + col;
#pragma unroll
            for (int v = 0; v < 4; ++v)
                zx[base + (size_t)v * NG] = (_Float16)(acc[mi][ni][v] + bv);
        }
    }
}

// ---- persistent LSTM recurrence ----
// 64 blocks = 4 batch-groups(16 batches) x 16 h-blocks(32 units). 4 waves, N-split,
// Wh register-resident. Exchange: SELF-VALIDATING 16B chunks {4 bf16, step tag, pad}
// stored fire-and-forget (per-lane 16B store = one coherence-point transaction).
// No sentinel, no ack, no fences. Consumer polls its 8 chunks (1 waitcnt); tag
// match => payload valid. hx layout: [parity][gb][producer gh][chunk 0..127]x16B.
__global__ __launch_bounds__(256, 1) void lstm_rec(
    const _Float16* __restrict__ zx, const unsigned short* __restrict__ WhT,
    const float* __restrict__ c0, const float* __restrict__ h0,
    const int* __restrict__ lengths, const int* __restrict__ revp,
    float* __restrict__ out, unsigned int* __restrict__ hx)
{
    __shared__ unsigned short h_lds[16][520];   // 16 batches x 512 units (+pad)
    __shared__ unsigned short h_next[16][32];   // this block's produced tile

    const int bid = blockIdx.x;
    const int gb = bid & 3, gh = bid >> 2;
    const int tid = threadIdx.x;
    const int lane = tid & 63, w = tid >> 6;
    const int b0 = gb * 16, u0 = gh * 32;
    const int rev = revp[0];

    const int colh = lane & 15;
    const int rr = (lane >> 4) << 2;   // batch base within group (MFMA D rows)
    const int cg = colh >> 3;          // gate-pair selector (0:{i,g} 1:{f,o})
    const int cu = colh & 7;
    const int uu = w * 8 + cu;         // unit within block (0..31)
    const int khw = (lane >> 4) << 3;  // k-offset within 32-chunk

    int len_v[4]; float c[4];
#pragma unroll
    for (int v = 0; v < 4; ++v) {
        len_v[v] = lengths[b0 + rr + v];
        c[v] = c0[(size_t)(b0 + rr + v) * H_ + u0 + uu];
    }

    // Wh fragments: bw[kk][ni] for gate = ni*2+cg, unit = u0+uu, k = kk*32+khw+0..7
    short8 bw[16][2];
#pragma unroll
    for (int ni = 0; ni < 2; ++ni) {
        const unsigned short* src = WhT + (size_t)((ni * 2 + cg) * H_ + u0 + uu) * D_ + khw;
#pragma unroll
        for (int kk = 0; kk < 16; ++kk)
            bw[kk][ni] = *(const short8*)(src + kk * 32);
    }

    float zxv[2][4];
#pragma unroll
    for (int ni = 0; ni < 2; ++ni)
#pragma unroll
        for (int v = 0; v < 4; ++v)
            zxv[ni][v] = (float)zx[((size_t)(b0 + rr + v) * T_) * NG + (ni * 2 + cg) * H_ + u0 + uu];

    // consumer map: thread -> batch row sr2 (=tid&15), producer ph (=tid>>4)
    const int sr2 = tid & 15;
    const int ph  = tid >> 4;
    const int scc = ph * 32;
    const int probeq = (sr2 + ph) & 7;

    // producer map (waves 0-1): lane L -> chunk L: batch L>>3, units (L&7)*4..+4
    const int L = (w << 6) | lane;      // 0..255; only L<128 publishes

    for (int s = 0; s < T_; ++s) {
        // ---- stage h(s)[16][512] -> LDS ----
        if (s == 0) {
            const float* hp = h0 + (size_t)(b0 + sr2) * H_ + scc;
#pragma unroll
            for (int q = 0; q < 4; ++q) {
                float4 f0 = *(const float4*)(hp + q * 8);
                float4 f1 = *(const float4*)(hp + q * 8 + 4);
                *(short8*)&h_lds[sr2][scc + q * 8] = pack8(f0, f1);
            }
        } else {
            // poll my 8 self-validating chunks from producer ph (single waitcnt)
            const unsigned int* dp = hx + ((((unsigned)(s & 1) * 4 + gb) * 16 + ph) << 9) + (sr2 << 5);
            uintx4 k0, k1, k2, k3, k4, k5, k6, k7;
            for (;;) {
                asm volatile(
                    "global_load_dwordx4 %0, %8, off sc0 sc1\n\t"
                    "global_load_dwordx4 %1, %8, off offset:16 sc0 sc1\n\t"
                    "global_load_dwordx4 %2, %8, off offset:32 sc0 sc1\n\t"
                    "global_load_dwordx4 %3, %8, off offset:48 sc0 sc1\n\t"
                    "global_load_dwordx4 %4, %8, off offset:64 sc0 sc1\n\t"
                    "global_load_dwordx4 %5, %8, off offset:80 sc0 sc1\n\t"
                    "global_load_dwordx4 %6, %8, off offset:96 sc0 sc1\n\t"
                    "global_load_dwordx4 %7, %8, off offset:112 sc0 sc1\n\t"
                    "s_waitcnt vmcnt(0)"
                    : "=&v"(k0), "=&v"(k1), "=&v"(k2), "=&v"(k3),
                      "=&v"(k4), "=&v"(k5), "=&v"(k6), "=&v"(k7)
                    : "v"(dp) : "memory");
                const unsigned int tg = (unsigned int)s;
                bool ok = (k0[2] == tg) & (k1[2] == tg) & (k2[2] == tg) & (k3[2] == tg) &
                          (k4[2] == tg) & (k5[2] == tg) & (k6[2] == tg) & (k7[2] == tg);
                if (ok) break;
                // cheap probe loop on one tag dword until it flips, then reload all
                const unsigned int* pp = dp + (probeq << 2) + 2;
                for (;;) {
                    unsigned int tv;
                    asm volatile("global_load_dword %0, %1, off sc0 sc1\n\t"
                                 "s_waitcnt vmcnt(0)"
                                 : "=v"(tv) : "v"(pp) : "memory");
                    if (tv == tg) break;
                    __builtin_amdgcn_s_sleep(1);
                }
            }
            uintx4 e;
            e[0] = k0[0]; e[1] = k0[1]; e[2] = k1[0]; e[3] = k1[1];
            *(uintx4*)&h_lds[sr2][scc]      = e;
            e[0] = k2[0]; e[1] = k2[1]; e[2] = k3[0]; e[3] = k3[1];
            *(uintx4*)&h_lds[sr2][scc + 8]  = e;
            e[0] = k4[0]; e[1] = k4[1]; e[2] = k5[0]; e[3] = k5[1];
            *(uintx4*)&h_lds[sr2][scc + 16] = e;
            e[0] = k6[0]; e[1] = k6[1]; e[2] = k7[0]; e[3] = k7[1];
            *(uintx4*)&h_lds[sr2][scc + 24] = e;
        }
        __syncthreads();   // (A) h_lds ready

        // ---- z = h @ Wh (full K per wave, 32 MFMA) ----
        floatx4 acc[2];
        acc[0] = (floatx4){0.f, 0.f, 0.f, 0.f};
        acc[1] = (floatx4){0.f, 0.f, 0.f, 0.f};
#pragma unroll
        for (int kk = 0; kk < 16; ++kk) {
            short8 af = *(const short8*)&h_lds[lane & 15][kk * 32 + khw];
            acc[0] = __builtin_amdgcn_mfma_f32_16x16x32_bf16(af, bw[kk][0], acc[0], 0, 0, 0);
            acc[1] = __builtin_amdgcn_mfma_f32_16x16x32_bf16(af, bw[kk][1], acc[1], 0, 0, 0);
        }

        // ---- gates; write h_next tile to LDS (cg==1 half owns it) ----
        float hn_v[4], cn_v[4];
#pragma unroll
        for (int v = 0; v < 4; ++v) {
            float own0 = acc[0][v] + zxv[0][v];        // gate cg
            float own1 = acc[1][v] + zxv[1][v];        // gate 2+cg
            float oth0 = __shfl_xor(own0, 8);          // gate 1-cg
            float oth1 = __shfl_xor(own1, 8);          // gate 3-cg
            float zi = cg ? oth0 : own0;
            float zf = cg ? own0 : oth0;
            float zg = cg ? oth1 : own1;
            float zo = cg ? own1 : oth1;
            float ig = sigm(zi), fg = sigm(zf);
            float gg = tanh_(zg), og = sigm(zo);
            float cn = fg * c[v] + ig * gg;
            float hn = og * tanh_(cn);
            c[v] = cn; cn_v[v] = cn; hn_v[v] = hn;
            if (cg == 1)
                h_next[rr + v][uu] = f2bf(hn);
        }
        __syncthreads();   // (B) h_next complete; h_lds free; MFMA reads done

        // ---- publish: waves 0-1 fire self-validating chunks (no ack, no sentinel) ----
        if (L < 128 && s + 1 < T_) {
            const int pb = L >> 3, pu = (L & 7) << 2;
            uint2 hv = *(const uint2*)&h_next[pb][pu];
            uintx4 ck;
            ck[0] = hv.x; ck[1] = hv.y; ck[2] = (unsigned int)(s + 1); ck[3] = 0u;
            unsigned int* dst = hx + ((((unsigned)((s + 1) & 1) * 4 + gb) * 16 + gh) << 9) + (L << 2);
            asm volatile("global_store_dwordx4 %0, %1, off sc0 sc1"
                         :: "v"(dst), "v"(ck) : "memory");
        }

        // ---- off-path: out stores + zx prefetch ----
#pragma unroll
        for (int v = 0; v < 4; ++v) {
            const int b = b0 + rr + v;
            const int ug = u0 + uu;
            int orig_t = rev ? ((T_ - 1 - s + len_v[v]) & (T_ - 1)) : s;
            if (cg == 0)
                out[((size_t)b * T_ + orig_t) * H_ + ug] = hn_v[v];
            if (s == len_v[v] - 1) {
                size_t fin = (size_t)B_ * T_ * H_;
                if (cg == 0) out[fin + (size_t)b * H_ + ug] = cn_v[v];
                else         out[fin + (size_t)B_ * H_ + (size_t)b * H_ + ug] = hn_v[v];
            }
        }
        if (s + 1 < T_) {
#pragma unroll
            for (int ni = 0; ni < 2; ++ni)
#pragma unroll
                for (int v = 0; v < 4; ++v)
                    zxv[ni][v] = (float)zx[((size_t)(b0 + rr + v) * T_ + s + 1) * NG +
                                           (ni * 2 + cg) * H_ + u0 + uu];
        }
    }
}

extern "C" void kernel_launch(void* const* d_in, const int* in_sizes, int n_in,
                              void* d_out, int out_size, void* d_ws, size_t ws_size,
                              hipStream_t stream)
{
    const float* x       = (const float*)d_in[0];
    const int*   lengths = (const int*)d_in[1];
    const float* c0      = (const float*)d_in[2];
    const float* h0      = (const float*)d_in[3];
    const float* Wi      = (const float*)d_in[4];
    const float* Wh      = (const float*)d_in[5];
    const float* bias    = (const float*)d_in[6];
    const int*   revp    = (const int*)d_in[7];
    float* out = (float*)d_out;

    char* ws = (char*)d_ws;
    const size_t OFF_WIT = 0;
    const size_t OFF_WHT = 2ull << 20;
    const size_t OFF_ZX  = 4ull << 20;
    const size_t OFF_HX  = OFF_ZX + (size_t)B_ * T_ * NG * 2;   // fp16 zx (128 MB)
    const size_t HX_BYTES = 2ull * 4 * 16 * 128 * 16;           // 256 KB tagged chunks
    const size_t NEED = OFF_HX + HX_BYTES;
    if (ws_size < NEED) return;

    unsigned short* WiT = (unsigned short*)(ws + OFF_WIT);
    unsigned short* WhT = (unsigned short*)(ws + OFF_WHT);
    _Float16* zx        = (_Float16*)(ws + OFF_ZX);
    unsigned int* hx    = (unsigned int*)(ws + OFF_HX);

    hipMemsetAsync(hx, 0, HX_BYTES, stream);   // invalidate tags each call
    dim3 gt(32, 8, 2);
    transpose_w<<<gt, 256, 0, stream>>>(Wi, Wh, WiT, WhT);
    dim3 g1(256, 16);
    zx_gemm<<<g1, 256, 0, stream>>>(x, lengths, WiT, bias, revp, zx);
    lstm_rec<<<64, 256, 0, stream>>>(zx, WhT, c0, h0, lengths, revp, out, hx);
}